// Round 1
// baseline (370.308 us; speedup 1.0000x reference)
//
#include <hip/hip_runtime.h>

// Batch-hard triplet loss, N=8192, D=128, fp32.
// Per row i: need minDotSame(i) and maxDotDiff(i); loss_i = relu(M + max(1-minDotSame,0) - (1-maxDotDiff)).
// Kernel 1: GEMM-shaped tiled dot products with fused min/max epilogue -> per-row partials in ws.
// Kernel 2: combine partials, compute mean.

#define NROWS 8192
#define DIM 128
#define MARGIN_F 0.3f
#define JSPLIT 4
#define BM 64
#define BN 64
#define NRB (NROWS / BM)          // 128 row blocks
#define JRANGE (NROWS / JSPLIT)   // 2048 cols per split
#define JTILES (JRANGE / BN)      // 32 tiles per split

__device__ __forceinline__ int swz(int r) { return (r ^ (r >> 3)) & 31; }

__global__ __launch_bounds__(256, 2) void tl_partial(
    const float* __restrict__ E, const int* __restrict__ labels,
    float* __restrict__ ws) {
  __shared__ float As[BM * DIM];   // 32 KB, swizzled 16B granules
  __shared__ float Bs[BN * DIM];   // 32 KB

  const int t = threadIdx.x;
  const int bid = blockIdx.x;
  const int rb = bid & (NRB - 1);  // row block 0..127
  const int s  = bid >> 7;         // j-split 0..3
  const int row0 = rb * BM;
  const int jbase0 = s * JRANGE;
  const int ty = t >> 4;           // 0..15 (row group of 4)
  const int tx = t & 15;           // 0..15 (col group of 4)

  // Hedge: detect int64 labels (all odd int32 words zero => 8-byte elements).
  bool odd0 = true;
  for (int q = 1; q < 128; q += 2) odd0 = odd0 && (labels[q] == 0);
  const int lstride = odd0 ? 2 : 1;

  // --- stage A tile (once), swizzled ---
#pragma unroll
  for (int it = 0; it < 8; ++it) {
    const int g = it * 256 + t;
    const int m = g >> 5;          // 0..63
    const int k4 = g & 31;         // 16B granule along K
    const float4 v = *(const float4*)&E[(row0 + m) * DIM + k4 * 4];
    *(float4*)&As[(m * 32 + (k4 ^ swz(m))) * 4] = v;
  }

  int rlab[4];
#pragma unroll
  for (int i = 0; i < 4; ++i) rlab[i] = labels[(row0 + ty * 4 + i) * lstride];

  float minS[4] = {1e30f, 1e30f, 1e30f, 1e30f};
  float maxDf[4] = {-1e30f, -1e30f, -1e30f, -1e30f};

  for (int jt = 0; jt < JTILES; ++jt) {
    const int jbase = jbase0 + jt * BN;

    // prefetch B tile to registers (loads issue before the barrier)
    float4 bv[8];
#pragma unroll
    for (int it = 0; it < 8; ++it) {
      const int g = it * 256 + t;
      const int r = g >> 5;
      const int k4 = g & 31;
      bv[it] = *(const float4*)&E[(jbase + r) * DIM + k4 * 4];
    }
    __syncthreads();   // previous tile's compute done (also orders A writes)
#pragma unroll
    for (int it = 0; it < 8; ++it) {
      const int g = it * 256 + t;
      const int r = g >> 5;
      const int k4 = g & 31;
      *(float4*)&Bs[(r * 32 + (k4 ^ swz(r))) * 4] = bv[it];
    }
    __syncthreads();

    float acc[4][4];
#pragma unroll
    for (int i = 0; i < 4; ++i)
#pragma unroll
      for (int j = 0; j < 4; ++j) acc[i][j] = 0.f;

#pragma unroll 4
    for (int k4 = 0; k4 < 32; ++k4) {
      float4 a[4], b[4];
#pragma unroll
      for (int i = 0; i < 4; ++i) {
        const int m = ty * 4 + i;
        a[i] = *(const float4*)&As[(m * 32 + (k4 ^ swz(m))) * 4];
      }
#pragma unroll
      for (int j = 0; j < 4; ++j) {
        const int n = tx * 4 + j;
        b[j] = *(const float4*)&Bs[(n * 32 + (k4 ^ swz(n))) * 4];
      }
#pragma unroll
      for (int i = 0; i < 4; ++i)
#pragma unroll
        for (int j = 0; j < 4; ++j) {
          acc[i][j] = fmaf(a[i].x, b[j].x, acc[i][j]);
          acc[i][j] = fmaf(a[i].y, b[j].y, acc[i][j]);
          acc[i][j] = fmaf(a[i].z, b[j].z, acc[i][j]);
          acc[i][j] = fmaf(a[i].w, b[j].w, acc[i][j]);
        }
    }

    // fused epilogue: running min(dot|same) / max(dot|diff)
#pragma unroll
    for (int j = 0; j < 4; ++j) {
      const int cl = labels[(jbase + tx * 4 + j) * lstride];
#pragma unroll
      for (int i = 0; i < 4; ++i) {
        const float d = acc[i][j];
        if (cl == rlab[i]) minS[i] = fminf(minS[i], d);
        else               maxDf[i] = fmaxf(maxDf[i], d);
      }
    }
  }

  // reduce across the 16 lanes (same ty) that share each row
#pragma unroll
  for (int i = 0; i < 4; ++i) {
    float v0 = minS[i], v1 = maxDf[i];
    for (int off = 1; off < 16; off <<= 1) {
      v0 = fminf(v0, __shfl_xor(v0, off));
      v1 = fmaxf(v1, __shfl_xor(v1, off));
    }
    minS[i] = v0; maxDf[i] = v1;
  }
  if (tx == 0) {
#pragma unroll
    for (int i = 0; i < 4; ++i) {
      const int row = row0 + ty * 4 + i;
      ws[s * NROWS + row] = minS[i];
      ws[JSPLIT * NROWS + s * NROWS + row] = maxDf[i];
    }
  }
}

__global__ void tl_reduce(const float* __restrict__ ws, float* __restrict__ out) {
  __shared__ float red[256];
  const int t = threadIdx.x;
  float sum = 0.f;
  for (int r = t; r < NROWS; r += 256) {
    float ms = 1e30f, md = -1e30f;
#pragma unroll
    for (int s2 = 0; s2 < JSPLIT; ++s2) {
      ms = fminf(ms, ws[s2 * NROWS + r]);
      md = fmaxf(md, ws[JSPLIT * NROWS + s2 * NROWS + r]);
    }
    const float hp = fmaxf(1.0f - ms, 0.0f);
    const float hn = 1.0f - md;
    sum += fmaxf(MARGIN_F + hp - hn, 0.0f);
  }
  red[t] = sum;
  __syncthreads();
  for (int off = 128; off > 0; off >>= 1) {
    if (t < off) red[t] += red[t + off];
    __syncthreads();
  }
  if (t == 0) out[0] = red[0] / (float)NROWS;
}

extern "C" void kernel_launch(void* const* d_in, const int* in_sizes, int n_in,
                              void* d_out, int out_size, void* d_ws, size_t ws_size,
                              hipStream_t stream) {
  const float* E = (const float*)d_in[0];
  const int* labels = (const int*)d_in[1];
  float* out = (float*)d_out;
  float* ws = (float*)d_ws;

  hipLaunchKernelGGL(tl_partial, dim3(NRB * JSPLIT), dim3(256), 0, stream,
                     E, labels, ws);
  hipLaunchKernelGGL(tl_reduce, dim3(1), dim3(256), 0, stream, ws, out);
}

// Round 2
// 106.028 us; speedup vs baseline: 3.4926x; 3.4926x over previous
//
#include <hip/hip_runtime.h>
#include <stdint.h>

// Batch-hard triplet loss, N=8192, D=128, fp32 input.
// dist = 1 - E@E^T. Per row: hp = max(1 - minDotSame, 0), hn = 1 - maxDotDiff,
// loss = mean(relu(MARGIN + hp - hn)).
// Strategy: bf16 split-precision MFMA emulation of the fp32 GEMM:
//   x = hi + lo (both bf16);  a.b ~= ah.bh + ah.bl + al.bh   (3 bf16 MFMAs)
// Fused min/max epilogue (never materialize the 8192^2 matrix).

#define NROWS 8192
#define DIM 128
#define MARGIN_F 0.3f
#define JSPLIT 4
#define JRANGE (NROWS / JSPLIT)   // 2048 cols per split
#define BM 128
#define BN 64
#define NRB (NROWS / BM)          // 64 row blocks
#define NTILES (JRANGE / BN)      // 32 col tiles per block

typedef float f32x4 __attribute__((ext_vector_type(4)));
typedef short s16x8 __attribute__((ext_vector_type(8)));
typedef unsigned short u16x8 __attribute__((ext_vector_type(8)));

__device__ __forceinline__ unsigned short bf16rn(float x) {
  union { float f; uint32_t u; } v; v.f = x;
  uint32_t r = v.u + 0x7FFFu + ((v.u >> 16) & 1u);
  return (unsigned short)(r >> 16);
}
__device__ __forceinline__ float bf16tof(unsigned short h) {
  union { uint32_t u; float f; } v; v.u = ((uint32_t)h) << 16;
  return v.f;
}
// convert 8 floats -> hi/lo bf16x8
__device__ __forceinline__ void cvt8(const float4 a, const float4 b,
                                     u16x8* h, u16x8* l) {
  float f[8] = {a.x, a.y, a.z, a.w, b.x, b.y, b.z, b.w};
  u16x8 hh, ll;
#pragma unroll
  for (int i = 0; i < 8; ++i) {
    unsigned short hv = bf16rn(f[i]);
    hh[i] = hv;
    ll[i] = bf16rn(f[i] - bf16tof(hv));
  }
  *h = hh; *l = ll;
}

__global__ __launch_bounds__(256, 1) void tl_partial(
    const float* __restrict__ E, const int* __restrict__ labels,
    float* __restrict__ ws) {
  // LDS: A(hi,lo) 64KB + B(hi,lo) double-buffered 64KB + reduce 1KB = 129KB
  __shared__ unsigned short Ah[BM * DIM];
  __shared__ unsigned short Al[BM * DIM];
  __shared__ unsigned short Bh[2][BN * DIM];
  __shared__ unsigned short Bl[2][BN * DIM];
  __shared__ float redmin[2][BM];
  __shared__ float redmax[2][BM];

  const int t = threadIdx.x;
  const int l = t & 63;
  const int wid = t >> 6;
  const int wr = wid >> 1, wc = wid & 1;   // wave covers rows wr*64.., cols wc*32..
  const int bid = blockIdx.x;
  const int rb = bid & (NRB - 1);
  const int s = bid >> 6;
  const int row0 = rb * BM;
  const int jbase0 = s * JRANGE;

  // label element-size probe (int32 vs int64 layout)
  bool odd0 = true;
  for (int q = 1; q < 128; q += 2) odd0 = odd0 && (labels[q] == 0);
  const int lstride = odd0 ? 2 : 1;

  // per-lane row labels: 16 rows (mi, j) at row = wr*64 + mi*16 + (l>>4)*4 + j
  int rlab[16];
#pragma unroll
  for (int mi = 0; mi < 4; ++mi)
#pragma unroll
    for (int j = 0; j < 4; ++j)
      rlab[mi * 4 + j] =
          labels[(row0 + wr * 64 + mi * 16 + (l >> 4) * 4 + j) * lstride];

  // ---- stage A tile (fp32 -> hi/lo bf16, XOR-swizzled granules) ----
#pragma unroll
  for (int it = 0; it < 8; ++it) {
    int gidx = it * 256 + t;          // 16B-granule id, 0..2047 (128 rows x 16)
    int row = gidx >> 4;
    int kg = gidx & 15;
    const float* p = &E[(size_t)(row0 + row) * DIM + kg * 8];
    float4 f0 = *(const float4*)p;
    float4 f1 = *(const float4*)(p + 4);
    u16x8 h, lo;
    cvt8(f0, f1, &h, &lo);
    int off = row * DIM + (kg ^ (row & 7)) * 8;
    *(u16x8*)&Ah[off] = h;
    *(u16x8*)&Al[off] = lo;
  }

  float4 bre[8];
  auto loadB = [&](int jt) {
#pragma unroll
    for (int it = 0; it < 4; ++it) {
      int gidx = it * 256 + t;        // 0..1023 (64 rows x 16 granules)
      int row = gidx >> 4;
      int kg = gidx & 15;
      const float* p = &E[(size_t)(jbase0 + jt * BN + row) * DIM + kg * 8];
      bre[2 * it] = *(const float4*)p;
      bre[2 * it + 1] = *(const float4*)(p + 4);
    }
  };
  auto writeB = [&](int buf) {
#pragma unroll
    for (int it = 0; it < 4; ++it) {
      int gidx = it * 256 + t;
      int row = gidx >> 4;
      int kg = gidx & 15;
      u16x8 h, lo;
      cvt8(bre[2 * it], bre[2 * it + 1], &h, &lo);
      int off = row * DIM + (kg ^ (row & 7)) * 8;
      *(u16x8*)&Bh[buf][off] = h;
      *(u16x8*)&Bl[buf][off] = lo;
    }
  };

  loadB(0);
  writeB(0);
  __syncthreads();

  float minS[16], maxD[16];
#pragma unroll
  for (int i = 0; i < 16; ++i) { minS[i] = 1e30f; maxD[i] = -1e30f; }

  for (int jt = 0; jt < NTILES; ++jt) {
    const int buf = jt & 1;
    if (jt + 1 < NTILES) loadB(jt + 1);   // issue next-tile global loads early

    f32x4 acc[4][2];
#pragma unroll
    for (int mi = 0; mi < 4; ++mi)
#pragma unroll
      for (int ni = 0; ni < 2; ++ni)
        acc[mi][ni] = (f32x4){0.f, 0.f, 0.f, 0.f};

#pragma unroll
    for (int ks = 0; ks < 4; ++ks) {
      const int kq = ks * 4 + (l >> 4);   // k granule
      s16x8 ah[4], al4[4], bh2[2], bl2[2];
#pragma unroll
      for (int mi = 0; mi < 4; ++mi) {
        int row = wr * 64 + mi * 16 + (l & 15);
        int off = row * DIM + (kq ^ (row & 7)) * 8;
        ah[mi] = *(const s16x8*)&Ah[off];
        al4[mi] = *(const s16x8*)&Al[off];
      }
#pragma unroll
      for (int ni = 0; ni < 2; ++ni) {
        int row = wc * 32 + ni * 16 + (l & 15);
        int off = row * DIM + (kq ^ (row & 7)) * 8;
        bh2[ni] = *(const s16x8*)&Bh[buf][off];
        bl2[ni] = *(const s16x8*)&Bl[buf][off];
      }
#pragma unroll
      for (int mi = 0; mi < 4; ++mi)
#pragma unroll
        for (int ni = 0; ni < 2; ++ni) {
          acc[mi][ni] = __builtin_amdgcn_mfma_f32_16x16x32_bf16(
              ah[mi], bh2[ni], acc[mi][ni], 0, 0, 0);
          acc[mi][ni] = __builtin_amdgcn_mfma_f32_16x16x32_bf16(
              ah[mi], bl2[ni], acc[mi][ni], 0, 0, 0);
          acc[mi][ni] = __builtin_amdgcn_mfma_f32_16x16x32_bf16(
              al4[mi], bh2[ni], acc[mi][ni], 0, 0, 0);
        }
    }

    // fused epilogue: running min(dot|same) / max(dot|diff)
    int clab[2];
#pragma unroll
    for (int ni = 0; ni < 2; ++ni)
      clab[ni] =
          labels[(jbase0 + jt * BN + wc * 32 + ni * 16 + (l & 15)) * lstride];
#pragma unroll
    for (int mi = 0; mi < 4; ++mi)
#pragma unroll
      for (int j = 0; j < 4; ++j) {
        const int idx = mi * 4 + j;
#pragma unroll
        for (int ni = 0; ni < 2; ++ni) {
          float d = acc[mi][ni][j];
          bool same = (clab[ni] == rlab[idx]);
          minS[idx] = (same && d < minS[idx]) ? d : minS[idx];
          maxD[idx] = (!same && d > maxD[idx]) ? d : maxD[idx];
        }
      }

    if (jt + 1 < NTILES) writeB(buf ^ 1);
    __syncthreads();
  }

  // reduce across the 16 lanes (same quarter-wave) holding different cols
#pragma unroll
  for (int i = 0; i < 16; ++i) {
    float v0 = minS[i], v1 = maxD[i];
#pragma unroll
    for (int off = 1; off < 16; off <<= 1) {
      v0 = fminf(v0, __shfl_xor(v0, off));
      v1 = fmaxf(v1, __shfl_xor(v1, off));
    }
    minS[i] = v0; maxD[i] = v1;
  }
  if ((l & 15) == 0) {
#pragma unroll
    for (int mi = 0; mi < 4; ++mi)
#pragma unroll
      for (int j = 0; j < 4; ++j) {
        int row = wr * 64 + mi * 16 + (l >> 4) * 4 + j;
        redmin[wc][row] = minS[mi * 4 + j];
        redmax[wc][row] = maxD[mi * 4 + j];
      }
  }
  __syncthreads();
  if (t < BM) {
    float m = fminf(redmin[0][t], redmin[1][t]);
    float M = fmaxf(redmax[0][t], redmax[1][t]);
    ws[s * NROWS + row0 + t] = m;
    ws[(JSPLIT + s) * NROWS + row0 + t] = M;
  }
}

__global__ void tl_reduce(const float* __restrict__ ws, float* __restrict__ out) {
  __shared__ float red[256];
  const int t = threadIdx.x;
  float sum = 0.f;
  for (int r = t; r < NROWS; r += 256) {
    float ms = 1e30f, md = -1e30f;
#pragma unroll
    for (int s2 = 0; s2 < JSPLIT; ++s2) {
      ms = fminf(ms, ws[s2 * NROWS + r]);
      md = fmaxf(md, ws[(JSPLIT + s2) * NROWS + r]);
    }
    const float hp = fmaxf(1.0f - ms, 0.0f);
    const float hn = 1.0f - md;
    sum += fmaxf(MARGIN_F + hp - hn, 0.0f);
  }
  red[t] = sum;
  __syncthreads();
  for (int off = 128; off > 0; off >>= 1) {
    if (t < off) red[t] += red[t + off];
    __syncthreads();
  }
  if (t == 0) out[0] = red[0] / (float)NROWS;
}

extern "C" void kernel_launch(void* const* d_in, const int* in_sizes, int n_in,
                              void* d_out, int out_size, void* d_ws, size_t ws_size,
                              hipStream_t stream) {
  const float* E = (const float*)d_in[0];
  const int* labels = (const int*)d_in[1];
  float* out = (float*)d_out;
  float* ws = (float*)d_ws;

  hipLaunchKernelGGL(tl_partial, dim3(NRB * JSPLIT), dim3(256), 0, stream,
                     E, labels, ws);
  hipLaunchKernelGGL(tl_reduce, dim3(1), dim3(256), 0, stream, ws, out);
}

// Round 3
// 96.248 us; speedup vs baseline: 3.8474x; 1.1016x over previous
//
#include <hip/hip_runtime.h>
#include <stdint.h>

// Batch-hard triplet loss, N=8192, D=128, fp32 input.
// R3: precompute bf16 hi/lo split of E into ws (4MB), then pure-bf16 MFMA
// GEMM (3-term split emulation: ah.bh + ah.bl + al.bh) with fused min/max
// epilogue. A-frags in registers, B staged via global_load_lds (swizzled).

#define NROWS 8192
#define DIM 128
#define MARGIN_F 0.3f

typedef float f32x4 __attribute__((ext_vector_type(4)));
typedef short s16x8 __attribute__((ext_vector_type(8)));
typedef unsigned short u16x8 __attribute__((ext_vector_type(8)));

__device__ __forceinline__ unsigned short bf16rn(float x) {
  union { float f; uint32_t u; } v; v.f = x;
  uint32_t r = v.u + 0x7FFFu + ((v.u >> 16) & 1u);
  return (unsigned short)(r >> 16);
}
__device__ __forceinline__ float bf16tof(unsigned short h) {
  union { uint32_t u; float f; } v; v.u = ((uint32_t)h) << 16;
  return v.f;
}
__device__ __forceinline__ void cvt8(const float4 a, const float4 b,
                                     u16x8* h, u16x8* l) {
  float f[8] = {a.x, a.y, a.z, a.w, b.x, b.y, b.z, b.w};
  u16x8 hh, ll;
#pragma unroll
  for (int i = 0; i < 8; ++i) {
    unsigned short hv = bf16rn(f[i]);
    hh[i] = hv;
    ll[i] = bf16rn(f[i] - bf16tof(hv));
  }
  *h = hh; *l = ll;
}

// ---------------- split pre-pass: E fp32 -> Ehi/Elo bf16 ----------------
__global__ __launch_bounds__(256) void tl_split(const float* __restrict__ E,
                                                unsigned short* __restrict__ hi,
                                                unsigned short* __restrict__ lo) {
  const int idx = blockIdx.x * 256 + threadIdx.x;  // 131072 threads x 8 elems
  const float4 f0 = ((const float4*)E)[2 * idx];
  const float4 f1 = ((const float4*)E)[2 * idx + 1];
  u16x8 h, l;
  cvt8(f0, f1, &h, &l);
  ((u16x8*)hi)[idx] = h;
  ((u16x8*)lo)[idx] = l;
}

// ---------------- main MFMA kernel ----------------
#define BM2 256
#define BN2 128
#define JSPLIT2 8
#define JRANGE2 (NROWS / JSPLIT2)  // 1024
#define NT2 (JRANGE2 / BN2)        // 8
#define NRB2 (NROWS / BM2)         // 32

__global__ __launch_bounds__(512, 2) void tl_mfma(
    const unsigned short* __restrict__ Ehi, const unsigned short* __restrict__ Elo,
    const int* __restrict__ labels, float* __restrict__ part) {
  __shared__ unsigned short Bh[2][BN2 * DIM];  // 64 KB
  __shared__ unsigned short Bl[2][BN2 * DIM];  // 64 KB
  __shared__ float redmin[2][BM2];
  __shared__ float redmax[2][BM2];

  const int t = threadIdx.x;
  const int l = t & 63;
  const int lq = l >> 4;           // 0..3
  const int lr = l & 15;           // 0..15
  const int wid = t >> 6;
  const int wr = wid >> 1;         // 0..3  (64-row group)
  const int wc = wid & 1;          // 0..1  (64-col group)
  const int s = blockIdx.x & 7;    // j-split == XCD (round-robin dispatch)
  const int rb = blockIdx.x >> 3;  // 0..31
  const int row0 = rb * BM2;
  const int jbase0 = s * JRANGE2;

  // label element-size probe (int64 vs int32)
  bool odd0 = true;
  for (int q = 1; q < 128; q += 2) odd0 = odd0 && (labels[q] == 0);
  const int lstride = odd0 ? 2 : 1;

  // packed row labels: byte j of rlabp[mi] = label(row0 + wr*64 + mi*16 + lq*4 + j)
  int rlabp[4];
#pragma unroll
  for (int mi = 0; mi < 4; ++mi) {
    int v = 0;
#pragma unroll
    for (int j = 0; j < 4; ++j)
      v |= labels[(row0 + wr * 64 + mi * 16 + lq * 4 + j) * lstride] << (8 * j);
    rlabp[mi] = v;
  }

  // A fragments (hi/lo) straight from global (L2-resident), held in regs
  s16x8 ahf[4][4], alf[4][4];  // [ks][mi]
#pragma unroll
  for (int ks = 0; ks < 4; ++ks)
#pragma unroll
    for (int mi = 0; mi < 4; ++mi) {
      const size_t off =
          (size_t)(row0 + wr * 64 + mi * 16 + lr) * DIM + (ks * 4 + lq) * 8;
      ahf[ks][mi] = *(const s16x8*)&Ehi[off];
      alf[ks][mi] = *(const s16x8*)&Elo[off];
    }

  // B staging: global_load_lds, linear LDS dest + inverse-swizzled source.
  auto stage = [&](int jt, int buf) {
#pragma unroll
    for (int i = 0; i < 4; ++i) {
      const int g = i * 512 + t;  // granule slot 0..2047 (row, kg')
      const int row = g >> 4;
      const int kg = (g & 15) ^ (row & 7);  // source granule (involution)
      const size_t goff = (size_t)(jbase0 + jt * BN2 + row) * DIM + kg * 8;
      __builtin_amdgcn_global_load_lds(
          (const __attribute__((address_space(1))) void*)&Ehi[goff],
          (__attribute__((address_space(3))) void*)&Bh[buf][g * 8], 16, 0, 0);
      __builtin_amdgcn_global_load_lds(
          (const __attribute__((address_space(1))) void*)&Elo[goff],
          (__attribute__((address_space(3))) void*)&Bl[buf][g * 8], 16, 0, 0);
    }
  };

  float minS[16], maxD[16];
#pragma unroll
  for (int i = 0; i < 16; ++i) { minS[i] = 1e30f; maxD[i] = -1e30f; }

  stage(0, 0);
  __syncthreads();

  for (int jt = 0; jt < NT2; ++jt) {
    const int buf = jt & 1;
    if (jt + 1 < NT2) stage(jt + 1, buf ^ 1);

    int clab[4];
#pragma unroll
    for (int ni = 0; ni < 4; ++ni)
      clab[ni] = labels[(jbase0 + jt * BN2 + wc * 64 + ni * 16 + lr) * lstride];

    f32x4 acc[4][4];
#pragma unroll
    for (int mi = 0; mi < 4; ++mi)
#pragma unroll
      for (int ni = 0; ni < 4; ++ni) acc[mi][ni] = (f32x4){0.f, 0.f, 0.f, 0.f};

#pragma unroll
    for (int ks = 0; ks < 4; ++ks) {
#pragma unroll
      for (int ni = 0; ni < 4; ++ni) {
        const int row = wc * 64 + ni * 16 + lr;
        const int off = row * DIM + ((ks * 4 + lq) ^ (row & 7)) * 8;
        const s16x8 bh = *(const s16x8*)&Bh[buf][off];
        const s16x8 bl = *(const s16x8*)&Bl[buf][off];
#pragma unroll
        for (int mi = 0; mi < 4; ++mi) {
          acc[mi][ni] = __builtin_amdgcn_mfma_f32_16x16x32_bf16(
              ahf[ks][mi], bh, acc[mi][ni], 0, 0, 0);
          acc[mi][ni] = __builtin_amdgcn_mfma_f32_16x16x32_bf16(
              ahf[ks][mi], bl, acc[mi][ni], 0, 0, 0);
          acc[mi][ni] = __builtin_amdgcn_mfma_f32_16x16x32_bf16(
              alf[ks][mi], bh, acc[mi][ni], 0, 0, 0);
        }
      }
    }

    // fused epilogue
#pragma unroll
    for (int mi = 0; mi < 4; ++mi)
#pragma unroll
      for (int j = 0; j < 4; ++j) {
        const int rl = (rlabp[mi] >> (8 * j)) & 255;
        const int idx = mi * 4 + j;
#pragma unroll
        for (int ni = 0; ni < 4; ++ni) {
          const float d = acc[mi][ni][j];
          const bool same = (clab[ni] == rl);
          minS[idx] = (same && d < minS[idx]) ? d : minS[idx];
          maxD[idx] = (!same && d > maxD[idx]) ? d : maxD[idx];
        }
      }
    __syncthreads();
  }

  // reduce across the 16 lanes (cols) sharing each row
#pragma unroll
  for (int i = 0; i < 16; ++i) {
    float v0 = minS[i], v1 = maxD[i];
#pragma unroll
    for (int off = 1; off < 16; off <<= 1) {
      v0 = fminf(v0, __shfl_xor(v0, off));
      v1 = fmaxf(v1, __shfl_xor(v1, off));
    }
    minS[i] = v0; maxD[i] = v1;
  }
  if (lr == 0) {
#pragma unroll
    for (int mi = 0; mi < 4; ++mi)
#pragma unroll
      for (int j = 0; j < 4; ++j) {
        const int row = wr * 64 + mi * 16 + lq * 4 + j;
        redmin[wc][row] = minS[mi * 4 + j];
        redmax[wc][row] = maxD[mi * 4 + j];
      }
  }
  __syncthreads();
  if (t < BM2) {
    const float m = fminf(redmin[0][t], redmin[1][t]);
    const float M = fmaxf(redmax[0][t], redmax[1][t]);
    part[(size_t)(row0 + t) * 16 + s] = m;
    part[(size_t)(row0 + t) * 16 + 8 + s] = M;
  }
}

__global__ __launch_bounds__(1024) void tl_reduce2(const float* __restrict__ part,
                                                   float* __restrict__ out) {
  __shared__ float red[1024];
  const int t = threadIdx.x;
  float sum = 0.f;
#pragma unroll
  for (int rr = 0; rr < NROWS / 1024; ++rr) {
    const int row = rr * 1024 + t;
    const float4 a = *(const float4*)&part[row * 16];
    const float4 b = *(const float4*)&part[row * 16 + 4];
    const float4 c = *(const float4*)&part[row * 16 + 8];
    const float4 d = *(const float4*)&part[row * 16 + 12];
    const float ms = fminf(fminf(fminf(a.x, a.y), fminf(a.z, a.w)),
                           fminf(fminf(b.x, b.y), fminf(b.z, b.w)));
    const float md = fmaxf(fmaxf(fmaxf(c.x, c.y), fmaxf(c.z, c.w)),
                           fmaxf(fmaxf(d.x, d.y), fmaxf(d.z, d.w)));
    const float hp = fmaxf(1.0f - ms, 0.0f);
    const float hn = 1.0f - md;
    sum += fmaxf(MARGIN_F + hp - hn, 0.0f);
  }
  red[t] = sum;
  __syncthreads();
  for (int off = 512; off > 0; off >>= 1) {
    if (t < off) red[t] += red[t + off];
    __syncthreads();
  }
  if (t == 0) out[0] = red[0] / (float)NROWS;
}

// ================= fallback (R2, proven): used if ws too small =================
#define FJSPLIT 4
#define FJRANGE (NROWS / FJSPLIT)
#define FBM 128
#define FBN 64
#define FNRB (NROWS / FBM)
#define FNT (FJRANGE / FBN)

__global__ __launch_bounds__(256, 1) void tl_partial_fb(
    const float* __restrict__ E, const int* __restrict__ labels,
    float* __restrict__ ws) {
  __shared__ unsigned short Ah[FBM * DIM];
  __shared__ unsigned short Al[FBM * DIM];
  __shared__ unsigned short Bhs[2][FBN * DIM];
  __shared__ unsigned short Bls[2][FBN * DIM];
  __shared__ float redmin[2][FBM];
  __shared__ float redmax[2][FBM];

  const int t = threadIdx.x;
  const int l = t & 63;
  const int wid = t >> 6;
  const int wr = wid >> 1, wc = wid & 1;
  const int bid = blockIdx.x;
  const int rb = bid & (FNRB - 1);
  const int s = bid >> 6;
  const int row0 = rb * FBM;
  const int jbase0 = s * FJRANGE;

  bool odd0 = true;
  for (int q = 1; q < 128; q += 2) odd0 = odd0 && (labels[q] == 0);
  const int lstride = odd0 ? 2 : 1;

  int rlab[16];
#pragma unroll
  for (int mi = 0; mi < 4; ++mi)
#pragma unroll
    for (int j = 0; j < 4; ++j)
      rlab[mi * 4 + j] =
          labels[(row0 + wr * 64 + mi * 16 + (l >> 4) * 4 + j) * lstride];

#pragma unroll
  for (int it = 0; it < 8; ++it) {
    int gidx = it * 256 + t;
    int row = gidx >> 4;
    int kg = gidx & 15;
    const float* p = &E[(size_t)(row0 + row) * DIM + kg * 8];
    float4 f0 = *(const float4*)p;
    float4 f1 = *(const float4*)(p + 4);
    u16x8 h, lo;
    cvt8(f0, f1, &h, &lo);
    int off = row * DIM + (kg ^ (row & 7)) * 8;
    *(u16x8*)&Ah[off] = h;
    *(u16x8*)&Al[off] = lo;
  }

  float4 bre[8];
  auto loadB = [&](int jt) {
#pragma unroll
    for (int it = 0; it < 4; ++it) {
      int gidx = it * 256 + t;
      int row = gidx >> 4;
      int kg = gidx & 15;
      const float* p = &E[(size_t)(jbase0 + jt * FBN + row) * DIM + kg * 8];
      bre[2 * it] = *(const float4*)p;
      bre[2 * it + 1] = *(const float4*)(p + 4);
    }
  };
  auto writeB = [&](int buf) {
#pragma unroll
    for (int it = 0; it < 4; ++it) {
      int gidx = it * 256 + t;
      int row = gidx >> 4;
      int kg = gidx & 15;
      u16x8 h, lo;
      cvt8(bre[2 * it], bre[2 * it + 1], &h, &lo);
      int off = row * DIM + (kg ^ (row & 7)) * 8;
      *(u16x8*)&Bhs[buf][off] = h;
      *(u16x8*)&Bls[buf][off] = lo;
    }
  };

  loadB(0);
  writeB(0);
  __syncthreads();

  float minS[16], maxD[16];
#pragma unroll
  for (int i = 0; i < 16; ++i) { minS[i] = 1e30f; maxD[i] = -1e30f; }

  for (int jt = 0; jt < FNT; ++jt) {
    const int buf = jt & 1;
    if (jt + 1 < FNT) loadB(jt + 1);

    f32x4 acc[4][2];
#pragma unroll
    for (int mi = 0; mi < 4; ++mi)
#pragma unroll
      for (int ni = 0; ni < 2; ++ni) acc[mi][ni] = (f32x4){0.f, 0.f, 0.f, 0.f};

#pragma unroll
    for (int ks = 0; ks < 4; ++ks) {
      const int kq = ks * 4 + (l >> 4);
      s16x8 ah[4], al4[4], bh2[2], bl2[2];
#pragma unroll
      for (int mi = 0; mi < 4; ++mi) {
        int row = wr * 64 + mi * 16 + (l & 15);
        int off = row * DIM + (kq ^ (row & 7)) * 8;
        ah[mi] = *(const s16x8*)&Ah[off];
        al4[mi] = *(const s16x8*)&Al[off];
      }
#pragma unroll
      for (int ni = 0; ni < 2; ++ni) {
        int row = wc * 32 + ni * 16 + (l & 15);
        int off = row * DIM + (kq ^ (row & 7)) * 8;
        bh2[ni] = *(const s16x8*)&Bhs[buf][off];
        bl2[ni] = *(const s16x8*)&Bls[buf][off];
      }
#pragma unroll
      for (int mi = 0; mi < 4; ++mi)
#pragma unroll
        for (int ni = 0; ni < 2; ++ni) {
          acc[mi][ni] = __builtin_amdgcn_mfma_f32_16x16x32_bf16(
              ah[mi], bh2[ni], acc[mi][ni], 0, 0, 0);
          acc[mi][ni] = __builtin_amdgcn_mfma_f32_16x16x32_bf16(
              ah[mi], bl2[ni], acc[mi][ni], 0, 0, 0);
          acc[mi][ni] = __builtin_amdgcn_mfma_f32_16x16x32_bf16(
              al4[mi], bh2[ni], acc[mi][ni], 0, 0, 0);
        }
    }

    int clab[2];
#pragma unroll
    for (int ni = 0; ni < 2; ++ni)
      clab[ni] =
          labels[(jbase0 + jt * FBN + wc * 32 + ni * 16 + (l & 15)) * lstride];
#pragma unroll
    for (int mi = 0; mi < 4; ++mi)
#pragma unroll
      for (int j = 0; j < 4; ++j) {
        const int idx = mi * 4 + j;
#pragma unroll
        for (int ni = 0; ni < 2; ++ni) {
          float d = acc[mi][ni][j];
          bool same = (clab[ni] == rlab[idx]);
          minS[idx] = (same && d < minS[idx]) ? d : minS[idx];
          maxD[idx] = (!same && d > maxD[idx]) ? d : maxD[idx];
        }
      }

    if (jt + 1 < FNT) writeB(buf ^ 1);
    __syncthreads();
  }

#pragma unroll
  for (int i = 0; i < 16; ++i) {
    float v0 = minS[i], v1 = maxD[i];
#pragma unroll
    for (int off = 1; off < 16; off <<= 1) {
      v0 = fminf(v0, __shfl_xor(v0, off));
      v1 = fmaxf(v1, __shfl_xor(v1, off));
    }
    minS[i] = v0; maxD[i] = v1;
  }
  if ((l & 15) == 0) {
#pragma unroll
    for (int mi = 0; mi < 4; ++mi)
#pragma unroll
      for (int j = 0; j < 4; ++j) {
        int row = wr * 64 + mi * 16 + (l >> 4) * 4 + j;
        redmin[wc][row] = minS[mi * 4 + j];
        redmax[wc][row] = maxD[mi * 4 + j];
      }
  }
  __syncthreads();
  if (t < FBM) {
    float m = fminf(redmin[0][t], redmin[1][t]);
    float M = fmaxf(redmax[0][t], redmax[1][t]);
    ws[s * NROWS + row0 + t] = m;
    ws[(FJSPLIT + s) * NROWS + row0 + t] = M;
  }
}

__global__ void tl_reduce_fb(const float* __restrict__ ws, float* __restrict__ out) {
  __shared__ float red[256];
  const int t = threadIdx.x;
  float sum = 0.f;
  for (int r = t; r < NROWS; r += 256) {
    float ms = 1e30f, md = -1e30f;
#pragma unroll
    for (int s2 = 0; s2 < FJSPLIT; ++s2) {
      ms = fminf(ms, ws[s2 * NROWS + r]);
      md = fmaxf(md, ws[(FJSPLIT + s2) * NROWS + r]);
    }
    const float hp = fmaxf(1.0f - ms, 0.0f);
    const float hn = 1.0f - md;
    sum += fmaxf(MARGIN_F + hp - hn, 0.0f);
  }
  red[t] = sum;
  __syncthreads();
  for (int off = 128; off > 0; off >>= 1) {
    if (t < off) red[t] += red[t + off];
    __syncthreads();
  }
  if (t == 0) out[0] = red[0] / (float)NROWS;
}

extern "C" void kernel_launch(void* const* d_in, const int* in_sizes, int n_in,
                              void* d_out, int out_size, void* d_ws, size_t ws_size,
                              hipStream_t stream) {
  const float* E = (const float*)d_in[0];
  const int* labels = (const int*)d_in[1];
  float* out = (float*)d_out;

  const size_t HALF = (size_t)NROWS * DIM;         // 1048576 elems
  const size_t need = HALF * 2 * 2 + (size_t)NROWS * 16 * 4;  // 4MB + 512KB

  if (ws_size >= need) {
    unsigned short* Ehi = (unsigned short*)d_ws;
    unsigned short* Elo = Ehi + HALF;
    float* part = (float*)((char*)d_ws + HALF * 4);
    hipLaunchKernelGGL(tl_split, dim3(512), dim3(256), 0, stream, E, Ehi, Elo);
    hipLaunchKernelGGL(tl_mfma, dim3(NRB2 * JSPLIT2), dim3(512), 0, stream,
                       Ehi, Elo, labels, part);
    hipLaunchKernelGGL(tl_reduce2, dim3(1), dim3(1024), 0, stream, part, out);
  } else {
    float* ws = (float*)d_ws;
    hipLaunchKernelGGL(tl_partial_fb, dim3(FNRB * FJSPLIT), dim3(256), 0, stream,
                       E, labels, ws);
    hipLaunchKernelGGL(tl_reduce_fb, dim3(1), dim3(256), 0, stream, ws, out);
  }
}

// Round 4
// 83.858 us; speedup vs baseline: 4.4159x; 1.1478x over previous
//
#include <hip/hip_runtime.h>
#include <stdint.h>

// Batch-hard triplet loss, N=8192, D=128, fp32 input.
// R4: pre-split E into bf16 hi/lo (ws). Main kernel: 3-term bf16 MFMA GEMM
// (ah.bh + ah.bl + al.bh) with fused min/max epilogue.
// Fix vs R3: wave tile 64x32 (was 64x64) -> acc 32 regs, total ~225 VGPR,
// no spills (R3 spilled ~25MB/dispatch). sched_barrier keeps B-prefetch
// (global_load_lds) issued before the MFMA block. 2-stage final reduce.

#define NROWS 8192
#define DIM 128
#define MARGIN_F 0.3f

typedef float f32x4 __attribute__((ext_vector_type(4)));
typedef short s16x8 __attribute__((ext_vector_type(8)));
typedef unsigned short u16x8 __attribute__((ext_vector_type(8)));

__device__ __forceinline__ unsigned short bf16rn(float x) {
  union { float f; uint32_t u; } v; v.f = x;
  uint32_t r = v.u + 0x7FFFu + ((v.u >> 16) & 1u);
  return (unsigned short)(r >> 16);
}
__device__ __forceinline__ float bf16tof(unsigned short h) {
  union { uint32_t u; float f; } v; v.u = ((uint32_t)h) << 16;
  return v.f;
}
__device__ __forceinline__ void cvt8(const float4 a, const float4 b,
                                     u16x8* h, u16x8* l) {
  float f[8] = {a.x, a.y, a.z, a.w, b.x, b.y, b.z, b.w};
  u16x8 hh, ll;
#pragma unroll
  for (int i = 0; i < 8; ++i) {
    unsigned short hv = bf16rn(f[i]);
    hh[i] = hv;
    ll[i] = bf16rn(f[i] - bf16tof(hv));
  }
  *h = hh; *l = ll;
}

// ---------------- split pre-pass: E fp32 -> Ehi/Elo bf16 ----------------
__global__ __launch_bounds__(256) void tl_split(const float* __restrict__ E,
                                                unsigned short* __restrict__ hi,
                                                unsigned short* __restrict__ lo) {
  const int idx = blockIdx.x * 256 + threadIdx.x;  // 131072 threads x 8 elems
  const float4 f0 = ((const float4*)E)[2 * idx];
  const float4 f1 = ((const float4*)E)[2 * idx + 1];
  u16x8 h, l;
  cvt8(f0, f1, &h, &l);
  ((u16x8*)hi)[idx] = h;
  ((u16x8*)lo)[idx] = l;
}

// ---------------- main MFMA kernel ----------------
// 512 threads = 8 waves, wave grid 2 (wr) x 4 (wc). Wave tile 64 rows x 32 cols.
#define BM2 128
#define BN2 128
#define JSPLIT2 4
#define JRANGE2 (NROWS / JSPLIT2)  // 2048
#define NT2 (JRANGE2 / BN2)        // 16 tiles
#define NRB2 (NROWS / BM2)         // 64 row blocks

__global__ __launch_bounds__(512, 2) void tl_mfma(
    const unsigned short* __restrict__ Ehi, const unsigned short* __restrict__ Elo,
    const int* __restrict__ labels, float* __restrict__ part) {
  __shared__ unsigned short Bh[2][BN2 * DIM];  // 64 KB
  __shared__ unsigned short Bl[2][BN2 * DIM];  // 64 KB
  __shared__ float redmin[4][BM2];             // 2 KB
  __shared__ float redmax[4][BM2];             // 2 KB

  const int t = threadIdx.x;
  const int l = t & 63;
  const int lq = l >> 4;           // 0..3
  const int lr = l & 15;           // 0..15
  const int wid = t >> 6;
  const int wr = wid >> 2;         // 0..1  (64-row group)
  const int wc = wid & 3;          // 0..3  (32-col group)
  const int s = blockIdx.x & 3;    // j-split (XCD-stable: bid%8 fixes s)
  const int rb = blockIdx.x >> 2;  // 0..63
  const int row0 = rb * BM2;
  const int jbase0 = s * JRANGE2;

  // label element-size probe (int64 vs int32): odd 32-bit words all zero
  bool odd0 = true;
  const int4* lp4 = (const int4*)labels;
#pragma unroll
  for (int q = 0; q < 8; ++q) {
    int4 v = lp4[q];
    odd0 = odd0 && (v.y == 0) && (v.w == 0);
  }
  const int lstride = odd0 ? 2 : 1;

  // packed row labels: byte j of rlabp[mi] = label(row0+wr*64+mi*16+lq*4+j)
  int rlabp[4];
#pragma unroll
  for (int mi = 0; mi < 4; ++mi) {
    int v = 0;
#pragma unroll
    for (int j = 0; j < 4; ++j)
      v |= labels[(row0 + wr * 64 + mi * 16 + lq * 4 + j) * lstride] << (8 * j);
    rlabp[mi] = v;
  }

  // A fragments (hi/lo) straight from global (L2-resident), held in regs.
  // 16+16 s16x8 = 128 VGPR.
  s16x8 ahf[4][4], alf[4][4];  // [ks][mi]
#pragma unroll
  for (int ks = 0; ks < 4; ++ks)
#pragma unroll
    for (int mi = 0; mi < 4; ++mi) {
      const size_t off =
          (size_t)(row0 + wr * 64 + mi * 16 + lr) * DIM + (ks * 4 + lq) * 8;
      ahf[ks][mi] = *(const s16x8*)&Ehi[off];
      alf[ks][mi] = *(const s16x8*)&Elo[off];
    }

  // B staging: global_load_lds, linear LDS dest + inverse-swizzled source.
  auto stage = [&](int jt, int buf) {
#pragma unroll
    for (int i = 0; i < 4; ++i) {
      const int g = i * 512 + t;            // granule slot 0..2047
      const int row = g >> 4;
      const int kg = (g & 15) ^ (row & 7);  // source granule (involution)
      const size_t goff = (size_t)(jbase0 + jt * BN2 + row) * DIM + kg * 8;
      __builtin_amdgcn_global_load_lds(
          (const __attribute__((address_space(1))) void*)&Ehi[goff],
          (__attribute__((address_space(3))) void*)&Bh[buf][g * 8], 16, 0, 0);
      __builtin_amdgcn_global_load_lds(
          (const __attribute__((address_space(1))) void*)&Elo[goff],
          (__attribute__((address_space(3))) void*)&Bl[buf][g * 8], 16, 0, 0);
    }
  };

  float minS[16], maxD[16];
#pragma unroll
  for (int i = 0; i < 16; ++i) { minS[i] = 1e30f; maxD[i] = -1e30f; }

  stage(0, 0);
  __syncthreads();

  for (int jt = 0; jt < NT2; ++jt) {
    const int buf = jt & 1;
    if (jt + 1 < NT2) stage(jt + 1, buf ^ 1);

    int clab[2];
#pragma unroll
    for (int ni = 0; ni < 2; ++ni)
      clab[ni] = labels[(jbase0 + jt * BN2 + wc * 32 + ni * 16 + lr) * lstride];

    // keep prefetch + label loads issued above; MFMAs below
    __builtin_amdgcn_sched_barrier(0);

    f32x4 acc[4][2];
#pragma unroll
    for (int mi = 0; mi < 4; ++mi)
#pragma unroll
      for (int ni = 0; ni < 2; ++ni) acc[mi][ni] = (f32x4){0.f, 0.f, 0.f, 0.f};

#pragma unroll
    for (int ks = 0; ks < 4; ++ks) {
      s16x8 bh2[2], bl2[2];
#pragma unroll
      for (int ni = 0; ni < 2; ++ni) {
        const int row = wc * 32 + ni * 16 + lr;
        const int off = row * DIM + ((ks * 4 + lq) ^ (row & 7)) * 8;
        bh2[ni] = *(const s16x8*)&Bh[buf][off];
        bl2[ni] = *(const s16x8*)&Bl[buf][off];
      }
#pragma unroll
      for (int mi = 0; mi < 4; ++mi)
#pragma unroll
        for (int ni = 0; ni < 2; ++ni) {
          acc[mi][ni] = __builtin_amdgcn_mfma_f32_16x16x32_bf16(
              ahf[ks][mi], bh2[ni], acc[mi][ni], 0, 0, 0);
          acc[mi][ni] = __builtin_amdgcn_mfma_f32_16x16x32_bf16(
              ahf[ks][mi], bl2[ni], acc[mi][ni], 0, 0, 0);
          acc[mi][ni] = __builtin_amdgcn_mfma_f32_16x16x32_bf16(
              alf[ks][mi], bh2[ni], acc[mi][ni], 0, 0, 0);
        }
    }

    // fused epilogue: running min(dot|same) / max(dot|diff)
#pragma unroll
    for (int mi = 0; mi < 4; ++mi)
#pragma unroll
      for (int j = 0; j < 4; ++j) {
        const int rl = (rlabp[mi] >> (8 * j)) & 255;
        const int idx = mi * 4 + j;
#pragma unroll
        for (int ni = 0; ni < 2; ++ni) {
          const float d = acc[mi][ni][j];
          const bool same = (clab[ni] == rl);
          minS[idx] = (same && d < minS[idx]) ? d : minS[idx];
          maxD[idx] = (!same && d > maxD[idx]) ? d : maxD[idx];
        }
      }
    __syncthreads();
  }

  // reduce across the 16 lanes (cols) sharing each row
#pragma unroll
  for (int i = 0; i < 16; ++i) {
    float v0 = minS[i], v1 = maxD[i];
#pragma unroll
    for (int off = 1; off < 16; off <<= 1) {
      v0 = fminf(v0, __shfl_xor(v0, off));
      v1 = fmaxf(v1, __shfl_xor(v1, off));
    }
    minS[i] = v0; maxD[i] = v1;
  }
  if (lr == 0) {
#pragma unroll
    for (int mi = 0; mi < 4; ++mi)
#pragma unroll
      for (int j = 0; j < 4; ++j) {
        const int row = wr * 64 + mi * 16 + lq * 4 + j;
        redmin[wc][row] = minS[mi * 4 + j];
        redmax[wc][row] = maxD[mi * 4 + j];
      }
  }
  __syncthreads();
  if (t < BM2) {
    const float m = fminf(fminf(redmin[0][t], redmin[1][t]),
                          fminf(redmin[2][t], redmin[3][t]));
    const float M = fmaxf(fmaxf(redmax[0][t], redmax[1][t]),
                          fmaxf(redmax[2][t], redmax[3][t]));
    part[(size_t)(row0 + t) * 8 + s] = m;
    part[(size_t)(row0 + t) * 8 + 4 + s] = M;
  }
}

// ---------------- 2-stage final reduce ----------------
__global__ __launch_bounds__(256) void tl_reduce_a(const float* __restrict__ part,
                                                   float* __restrict__ partial) {
  __shared__ float red[256];
  const int t = threadIdx.x;
  const int row = blockIdx.x * 256 + t;  // 32 blocks x 256 rows
  const float4 mn = *(const float4*)&part[(size_t)row * 8];
  const float4 mx = *(const float4*)&part[(size_t)row * 8 + 4];
  const float ms = fminf(fminf(mn.x, mn.y), fminf(mn.z, mn.w));
  const float md = fmaxf(fmaxf(mx.x, mx.y), fmaxf(mx.z, mx.w));
  const float hp = fmaxf(1.0f - ms, 0.0f);
  const float hn = 1.0f - md;
  red[t] = fmaxf(MARGIN_F + hp - hn, 0.0f);
  __syncthreads();
  for (int off = 128; off > 0; off >>= 1) {
    if (t < off) red[t] += red[t + off];
    __syncthreads();
  }
  if (t == 0) partial[blockIdx.x] = red[0];
}

__global__ void tl_reduce_b(const float* __restrict__ partial,
                            float* __restrict__ out) {
  const int t = threadIdx.x;  // 64 threads
  float v = (t < 32) ? partial[t] : 0.f;
#pragma unroll
  for (int off = 1; off < 64; off <<= 1) v += __shfl_xor(v, off);
  if (t == 0) out[0] = v / (float)NROWS;
}

// ================= fallback (R2, proven): used if ws too small =================
#define FJSPLIT 4
#define FJRANGE (NROWS / FJSPLIT)
#define FBM 128
#define FBN 64
#define FNRB (NROWS / FBM)
#define FNT (FJRANGE / FBN)

__global__ __launch_bounds__(256, 1) void tl_partial_fb(
    const float* __restrict__ E, const int* __restrict__ labels,
    float* __restrict__ ws) {
  __shared__ unsigned short Ah[FBM * DIM];
  __shared__ unsigned short Al[FBM * DIM];
  __shared__ unsigned short Bhs[2][FBN * DIM];
  __shared__ unsigned short Bls[2][FBN * DIM];
  __shared__ float redmin[2][FBM];
  __shared__ float redmax[2][FBM];

  const int t = threadIdx.x;
  const int l = t & 63;
  const int wid = t >> 6;
  const int wr = wid >> 1, wc = wid & 1;
  const int bid = blockIdx.x;
  const int rb = bid & (FNRB - 1);
  const int s = bid >> 6;
  const int row0 = rb * FBM;
  const int jbase0 = s * FJRANGE;

  bool odd0 = true;
  for (int q = 1; q < 128; q += 2) odd0 = odd0 && (labels[q] == 0);
  const int lstride = odd0 ? 2 : 1;

  int rlab[16];
#pragma unroll
  for (int mi = 0; mi < 4; ++mi)
#pragma unroll
    for (int j = 0; j < 4; ++j)
      rlab[mi * 4 + j] =
          labels[(row0 + wr * 64 + mi * 16 + (l >> 4) * 4 + j) * lstride];

#pragma unroll
  for (int it = 0; it < 8; ++it) {
    int gidx = it * 256 + t;
    int row = gidx >> 4;
    int kg = gidx & 15;
    const float* p = &E[(size_t)(row0 + row) * DIM + kg * 8];
    float4 f0 = *(const float4*)p;
    float4 f1 = *(const float4*)(p + 4);
    u16x8 h, lo;
    cvt8(f0, f1, &h, &lo);
    int off = row * DIM + (kg ^ (row & 7)) * 8;
    *(u16x8*)&Ah[off] = h;
    *(u16x8*)&Al[off] = lo;
  }

  float4 bre[8];
  auto loadB = [&](int jt) {
#pragma unroll
    for (int it = 0; it < 4; ++it) {
      int gidx = it * 256 + t;
      int row = gidx >> 4;
      int kg = gidx & 15;
      const float* p = &E[(size_t)(jbase0 + jt * FBN + row) * DIM + kg * 8];
      bre[2 * it] = *(const float4*)p;
      bre[2 * it + 1] = *(const float4*)(p + 4);
    }
  };
  auto writeB = [&](int buf) {
#pragma unroll
    for (int it = 0; it < 4; ++it) {
      int gidx = it * 256 + t;
      int row = gidx >> 4;
      int kg = gidx & 15;
      u16x8 h, lo;
      cvt8(bre[2 * it], bre[2 * it + 1], &h, &lo);
      int off = row * DIM + (kg ^ (row & 7)) * 8;
      *(u16x8*)&Bhs[buf][off] = h;
      *(u16x8*)&Bls[buf][off] = lo;
    }
  };

  loadB(0);
  writeB(0);
  __syncthreads();

  float minS[16], maxD[16];
#pragma unroll
  for (int i = 0; i < 16; ++i) { minS[i] = 1e30f; maxD[i] = -1e30f; }

  for (int jt = 0; jt < FNT; ++jt) {
    const int buf = jt & 1;
    if (jt + 1 < FNT) loadB(jt + 1);

    f32x4 acc[4][2];
#pragma unroll
    for (int mi = 0; mi < 4; ++mi)
#pragma unroll
      for (int ni = 0; ni < 2; ++ni) acc[mi][ni] = (f32x4){0.f, 0.f, 0.f, 0.f};

#pragma unroll
    for (int ks = 0; ks < 4; ++ks) {
      const int kq = ks * 4 + (l >> 4);
      s16x8 ah[4], al4[4], bh2[2], bl2[2];
#pragma unroll
      for (int mi = 0; mi < 4; ++mi) {
        int row = wr * 64 + mi * 16 + (l & 15);
        int off = row * DIM + (kq ^ (row & 7)) * 8;
        ah[mi] = *(const s16x8*)&Ah[off];
        al4[mi] = *(const s16x8*)&Al[off];
      }
#pragma unroll
      for (int ni = 0; ni < 2; ++ni) {
        int row = wc * 32 + ni * 16 + (l & 15);
        int off = row * DIM + (kq ^ (row & 7)) * 8;
        bh2[ni] = *(const s16x8*)&Bhs[buf][off];
        bl2[ni] = *(const s16x8*)&Bls[buf][off];
      }
#pragma unroll
      for (int mi = 0; mi < 4; ++mi)
#pragma unroll
        for (int ni = 0; ni < 2; ++ni) {
          acc[mi][ni] = __builtin_amdgcn_mfma_f32_16x16x32_bf16(
              ah[mi], bh2[ni], acc[mi][ni], 0, 0, 0);
          acc[mi][ni] = __builtin_amdgcn_mfma_f32_16x16x32_bf16(
              ah[mi], bl2[ni], acc[mi][ni], 0, 0, 0);
          acc[mi][ni] = __builtin_amdgcn_mfma_f32_16x16x32_bf16(
              al4[mi], bh2[ni], acc[mi][ni], 0, 0, 0);
        }
    }

    int clab[2];
#pragma unroll
    for (int ni = 0; ni < 2; ++ni)
      clab[ni] =
          labels[(jbase0 + jt * FBN + wc * 32 + ni * 16 + (l & 15)) * lstride];
#pragma unroll
    for (int mi = 0; mi < 4; ++mi)
#pragma unroll
      for (int j = 0; j < 4; ++j) {
        const int idx = mi * 4 + j;
#pragma unroll
        for (int ni = 0; ni < 2; ++ni) {
          float d = acc[mi][ni][j];
          bool same = (clab[ni] == rlab[idx]);
          minS[idx] = (same && d < minS[idx]) ? d : minS[idx];
          maxD[idx] = (!same && d > maxD[idx]) ? d : maxD[idx];
        }
      }

    if (jt + 1 < FNT) writeB(buf ^ 1);
    __syncthreads();
  }

#pragma unroll
  for (int i = 0; i < 16; ++i) {
    float v0 = minS[i], v1 = maxD[i];
#pragma unroll
    for (int off = 1; off < 16; off <<= 1) {
      v0 = fminf(v0, __shfl_xor(v0, off));
      v1 = fmaxf(v1, __shfl_xor(v1, off));
    }
    minS[i] = v0; maxD[i] = v1;
  }
  if ((l & 15) == 0) {
#pragma unroll
    for (int mi = 0; mi < 4; ++mi)
#pragma unroll
      for (int j = 0; j < 4; ++j) {
        int row = wr * 64 + mi * 16 + (l >> 4) * 4 + j;
        redmin[wc][row] = minS[mi * 4 + j];
        redmax[wc][row] = maxD[mi * 4 + j];
      }
  }
  __syncthreads();
  if (t < FBM) {
    float m = fminf(redmin[0][t], redmin[1][t]);
    float M = fmaxf(redmax[0][t], redmax[1][t]);
    ws[s * NROWS + row0 + t] = m;
    ws[(FJSPLIT + s) * NROWS + row0 + t] = M;
  }
}

__global__ void tl_reduce_fb(const float* __restrict__ ws, float* __restrict__ out) {
  __shared__ float red[256];
  const int t = threadIdx.x;
  float sum = 0.f;
  for (int r = t; r < NROWS; r += 256) {
    float ms = 1e30f, md = -1e30f;
#pragma unroll
    for (int s2 = 0; s2 < FJSPLIT; ++s2) {
      ms = fminf(ms, ws[s2 * NROWS + r]);
      md = fmaxf(md, ws[(FJSPLIT + s2) * NROWS + r]);
    }
    const float hp = fmaxf(1.0f - ms, 0.0f);
    const float hn = 1.0f - md;
    sum += fmaxf(MARGIN_F + hp - hn, 0.0f);
  }
  red[t] = sum;
  __syncthreads();
  for (int off = 128; off > 0; off >>= 1) {
    if (t < off) red[t] += red[t + off];
    __syncthreads();
  }
  if (t == 0) out[0] = red[0] / (float)NROWS;
}

extern "C" void kernel_launch(void* const* d_in, const int* in_sizes, int n_in,
                              void* d_out, int out_size, void* d_ws, size_t ws_size,
                              hipStream_t stream) {
  const float* E = (const float*)d_in[0];
  const int* labels = (const int*)d_in[1];
  float* out = (float*)d_out;

  const size_t HALF = (size_t)NROWS * DIM;  // 1048576 elems
  const size_t partOff = HALF * 4;          // 4MB (Ehi+Elo, 2B each)
  const size_t need = partOff + (size_t)NROWS * 8 * 4 + 4096;

  if (ws_size >= need) {
    unsigned short* Ehi = (unsigned short*)d_ws;
    unsigned short* Elo = Ehi + HALF;
    float* part = (float*)((char*)d_ws + partOff);
    float* partial = part + (size_t)NROWS * 8;
    hipLaunchKernelGGL(tl_split, dim3(512), dim3(256), 0, stream, E, Ehi, Elo);
    hipLaunchKernelGGL(tl_mfma, dim3(NRB2 * JSPLIT2), dim3(512), 0, stream,
                       Ehi, Elo, labels, part);
    hipLaunchKernelGGL(tl_reduce_a, dim3(32), dim3(256), 0, stream, part, partial);
    hipLaunchKernelGGL(tl_reduce_b, dim3(1), dim3(64), 0, stream, partial, out);
  } else {
    float* ws = (float*)d_ws;
    hipLaunchKernelGGL(tl_partial_fb, dim3(FNRB * FJSPLIT), dim3(256), 0, stream,
                       E, labels, ws);
    hipLaunchKernelGGL(tl_reduce_fb, dim3(1), dim3(256), 0, stream, ws, out);
  }
}

// Round 5
// 83.801 us; speedup vs baseline: 4.4189x; 1.0007x over previous
//
#include <hip/hip_runtime.h>
#include <stdint.h>

// Batch-hard triplet loss, N=8192, D=128, fp32 input.
// R5: same structure as R4 (bf16 hi/lo split, 3-term MFMA emulation,
// A-frags in regs, B via global_load_lds swizzled, fused min/max epilogue).
// Fix: amdgpu_waves_per_eu(2,2) -> VGPR budget 256 (R4's allocator capped at
// 128 and spilled ~10.7MB/dispatch, which dominated runtime).

#define NROWS 8192
#define DIM 128
#define MARGIN_F 0.3f

typedef float f32x4 __attribute__((ext_vector_type(4)));
typedef short s16x8 __attribute__((ext_vector_type(8)));
typedef unsigned short u16x8 __attribute__((ext_vector_type(8)));

__device__ __forceinline__ unsigned short bf16rn(float x) {
  union { float f; uint32_t u; } v; v.f = x;
  uint32_t r = v.u + 0x7FFFu + ((v.u >> 16) & 1u);
  return (unsigned short)(r >> 16);
}
__device__ __forceinline__ float bf16tof(unsigned short h) {
  union { uint32_t u; float f; } v; v.u = ((uint32_t)h) << 16;
  return v.f;
}
__device__ __forceinline__ void cvt8(const float4 a, const float4 b,
                                     u16x8* h, u16x8* l) {
  float f[8] = {a.x, a.y, a.z, a.w, b.x, b.y, b.z, b.w};
  u16x8 hh, ll;
#pragma unroll
  for (int i = 0; i < 8; ++i) {
    unsigned short hv = bf16rn(f[i]);
    hh[i] = hv;
    ll[i] = bf16rn(f[i] - bf16tof(hv));
  }
  *h = hh; *l = ll;
}

// ---------------- split pre-pass: E fp32 -> Ehi/Elo bf16 ----------------
__global__ __launch_bounds__(256) void tl_split(const float* __restrict__ E,
                                                unsigned short* __restrict__ hi,
                                                unsigned short* __restrict__ lo) {
  const int idx = blockIdx.x * 256 + threadIdx.x;  // 131072 threads x 8 elems
  const float4 f0 = ((const float4*)E)[2 * idx];
  const float4 f1 = ((const float4*)E)[2 * idx + 1];
  u16x8 h, l;
  cvt8(f0, f1, &h, &l);
  ((u16x8*)hi)[idx] = h;
  ((u16x8*)lo)[idx] = l;
}

// ---------------- main MFMA kernel ----------------
// 512 threads = 8 waves, wave grid 2 (wr) x 4 (wc). Wave tile 64 rows x 32 cols.
#define BM2 128
#define BN2 128
#define JSPLIT2 4
#define JRANGE2 (NROWS / JSPLIT2)  // 2048
#define NT2 (JRANGE2 / BN2)        // 16 tiles
#define NRB2 (NROWS / BM2)         // 64 row blocks

__global__ __launch_bounds__(512)
__attribute__((amdgpu_waves_per_eu(2, 2)))
void tl_mfma(
    const unsigned short* __restrict__ Ehi, const unsigned short* __restrict__ Elo,
    const int* __restrict__ labels, float* __restrict__ part) {
  __shared__ unsigned short Bh[2][BN2 * DIM];  // 64 KB
  __shared__ unsigned short Bl[2][BN2 * DIM];  // 64 KB
  __shared__ float redmin[4][BM2];             // 2 KB
  __shared__ float redmax[4][BM2];             // 2 KB

  const int t = threadIdx.x;
  const int l = t & 63;
  const int lq = l >> 4;           // 0..3
  const int lr = l & 15;           // 0..15
  const int wid = t >> 6;
  const int wr = wid >> 2;         // 0..1  (64-row group)
  const int wc = wid & 3;          // 0..3  (32-col group)
  const int s = blockIdx.x & 3;    // j-split
  const int rb = blockIdx.x >> 2;  // 0..63
  const int row0 = rb * BM2;
  const int jbase0 = s * JRANGE2;

  // label element-size probe (int64 vs int32): odd 32-bit words all zero
  bool odd0 = true;
  const int4* lp4 = (const int4*)labels;
#pragma unroll
  for (int q = 0; q < 8; ++q) {
    int4 v = lp4[q];
    odd0 = odd0 && (v.y == 0) && (v.w == 0);
  }
  const int lstride = odd0 ? 2 : 1;

  // packed row labels: byte j of rlabp[mi] = label(row0+wr*64+mi*16+lq*4+j)
  int rlabp[4];
#pragma unroll
  for (int mi = 0; mi < 4; ++mi) {
    int v = 0;
#pragma unroll
    for (int j = 0; j < 4; ++j)
      v |= labels[(row0 + wr * 64 + mi * 16 + lq * 4 + j) * lstride] << (8 * j);
    rlabp[mi] = v;
  }

  // A fragments (hi/lo) straight from global (L2-resident), held in regs.
  // 16+16 s16x8 = 128 VGPR.
  s16x8 ahf[4][4], alf[4][4];  // [ks][mi]
#pragma unroll
  for (int ks = 0; ks < 4; ++ks)
#pragma unroll
    for (int mi = 0; mi < 4; ++mi) {
      const size_t off =
          (size_t)(row0 + wr * 64 + mi * 16 + lr) * DIM + (ks * 4 + lq) * 8;
      ahf[ks][mi] = *(const s16x8*)&Ehi[off];
      alf[ks][mi] = *(const s16x8*)&Elo[off];
    }

  // B staging: global_load_lds, linear LDS dest + inverse-swizzled source.
  auto stage = [&](int jt, int buf) {
#pragma unroll
    for (int i = 0; i < 4; ++i) {
      const int g = i * 512 + t;            // granule slot 0..2047
      const int row = g >> 4;
      const int kg = (g & 15) ^ (row & 7);  // source granule (involution)
      const size_t goff = (size_t)(jbase0 + jt * BN2 + row) * DIM + kg * 8;
      __builtin_amdgcn_global_load_lds(
          (const __attribute__((address_space(1))) void*)&Ehi[goff],
          (__attribute__((address_space(3))) void*)&Bh[buf][g * 8], 16, 0, 0);
      __builtin_amdgcn_global_load_lds(
          (const __attribute__((address_space(1))) void*)&Elo[goff],
          (__attribute__((address_space(3))) void*)&Bl[buf][g * 8], 16, 0, 0);
    }
  };

  float minS[16], maxD[16];
#pragma unroll
  for (int i = 0; i < 16; ++i) { minS[i] = 1e30f; maxD[i] = -1e30f; }

  stage(0, 0);
  __syncthreads();

  for (int jt = 0; jt < NT2; ++jt) {
    const int buf = jt & 1;
    if (jt + 1 < NT2) stage(jt + 1, buf ^ 1);

    int clab[2];
#pragma unroll
    for (int ni = 0; ni < 2; ++ni)
      clab[ni] = labels[(jbase0 + jt * BN2 + wc * 32 + ni * 16 + lr) * lstride];

    // keep prefetch + label loads issued above; MFMAs below
    __builtin_amdgcn_sched_barrier(0);

    f32x4 acc[4][2];
#pragma unroll
    for (int mi = 0; mi < 4; ++mi)
#pragma unroll
      for (int ni = 0; ni < 2; ++ni) acc[mi][ni] = (f32x4){0.f, 0.f, 0.f, 0.f};

#pragma unroll
    for (int ks = 0; ks < 4; ++ks) {
      s16x8 bh2[2], bl2[2];
#pragma unroll
      for (int ni = 0; ni < 2; ++ni) {
        const int row = wc * 32 + ni * 16 + lr;
        const int off = row * DIM + ((ks * 4 + lq) ^ (row & 7)) * 8;
        bh2[ni] = *(const s16x8*)&Bh[buf][off];
        bl2[ni] = *(const s16x8*)&Bl[buf][off];
      }
#pragma unroll
      for (int mi = 0; mi < 4; ++mi)
#pragma unroll
        for (int ni = 0; ni < 2; ++ni) {
          acc[mi][ni] = __builtin_amdgcn_mfma_f32_16x16x32_bf16(
              ahf[ks][mi], bh2[ni], acc[mi][ni], 0, 0, 0);
          acc[mi][ni] = __builtin_amdgcn_mfma_f32_16x16x32_bf16(
              ahf[ks][mi], bl2[ni], acc[mi][ni], 0, 0, 0);
          acc[mi][ni] = __builtin_amdgcn_mfma_f32_16x16x32_bf16(
              alf[ks][mi], bh2[ni], acc[mi][ni], 0, 0, 0);
        }
    }

    // fused epilogue: running min(dot|same) / max(dot|diff)
#pragma unroll
    for (int mi = 0; mi < 4; ++mi)
#pragma unroll
      for (int j = 0; j < 4; ++j) {
        const int rl = (rlabp[mi] >> (8 * j)) & 255;
        const int idx = mi * 4 + j;
#pragma unroll
        for (int ni = 0; ni < 2; ++ni) {
          const float d = acc[mi][ni][j];
          const bool same = (clab[ni] == rl);
          minS[idx] = (same && d < minS[idx]) ? d : minS[idx];
          maxD[idx] = (!same && d > maxD[idx]) ? d : maxD[idx];
        }
      }
    __syncthreads();
  }

  // reduce across the 16 lanes (cols) sharing each row
#pragma unroll
  for (int i = 0; i < 16; ++i) {
    float v0 = minS[i], v1 = maxD[i];
#pragma unroll
    for (int off = 1; off < 16; off <<= 1) {
      v0 = fminf(v0, __shfl_xor(v0, off));
      v1 = fmaxf(v1, __shfl_xor(v1, off));
    }
    minS[i] = v0; maxD[i] = v1;
  }
  if (lr == 0) {
#pragma unroll
    for (int mi = 0; mi < 4; ++mi)
#pragma unroll
      for (int j = 0; j < 4; ++j) {
        const int row = wr * 64 + mi * 16 + lq * 4 + j;
        redmin[wc][row] = minS[mi * 4 + j];
        redmax[wc][row] = maxD[mi * 4 + j];
      }
  }
  __syncthreads();
  if (t < BM2) {
    const float m = fminf(fminf(redmin[0][t], redmin[1][t]),
                          fminf(redmin[2][t], redmin[3][t]));
    const float M = fmaxf(fmaxf(redmax[0][t], redmax[1][t]),
                          fmaxf(redmax[2][t], redmax[3][t]));
    part[(size_t)(row0 + t) * 8 + s] = m;
    part[(size_t)(row0 + t) * 8 + 4 + s] = M;
  }
}

// ---------------- 2-stage final reduce ----------------
__global__ __launch_bounds__(256) void tl_reduce_a(const float* __restrict__ part,
                                                   float* __restrict__ partial) {
  __shared__ float red[256];
  const int t = threadIdx.x;
  const int row = blockIdx.x * 256 + t;  // 32 blocks x 256 rows
  const float4 mn = *(const float4*)&part[(size_t)row * 8];
  const float4 mx = *(const float4*)&part[(size_t)row * 8 + 4];
  const float ms = fminf(fminf(mn.x, mn.y), fminf(mn.z, mn.w));
  const float md = fmaxf(fmaxf(mx.x, mx.y), fmaxf(mx.z, mx.w));
  const float hp = fmaxf(1.0f - ms, 0.0f);
  const float hn = 1.0f - md;
  red[t] = fmaxf(MARGIN_F + hp - hn, 0.0f);
  __syncthreads();
  for (int off = 128; off > 0; off >>= 1) {
    if (t < off) red[t] += red[t + off];
    __syncthreads();
  }
  if (t == 0) partial[blockIdx.x] = red[0];
}

__global__ void tl_reduce_b(const float* __restrict__ partial,
                            float* __restrict__ out) {
  const int t = threadIdx.x;  // 64 threads
  float v = (t < 32) ? partial[t] : 0.f;
#pragma unroll
  for (int off = 1; off < 64; off <<= 1) v += __shfl_xor(v, off);
  if (t == 0) out[0] = v / (float)NROWS;
}

// ================= fallback (R2, proven): used if ws too small =================
#define FJSPLIT 4
#define FJRANGE (NROWS / FJSPLIT)
#define FBM 128
#define FBN 64
#define FNRB (NROWS / FBM)
#define FNT (FJRANGE / FBN)

__global__ __launch_bounds__(256, 1) void tl_partial_fb(
    const float* __restrict__ E, const int* __restrict__ labels,
    float* __restrict__ ws) {
  __shared__ unsigned short Ah[FBM * DIM];
  __shared__ unsigned short Al[FBM * DIM];
  __shared__ unsigned short Bhs[2][FBN * DIM];
  __shared__ unsigned short Bls[2][FBN * DIM];
  __shared__ float redmin[2][FBM];
  __shared__ float redmax[2][FBM];

  const int t = threadIdx.x;
  const int l = t & 63;
  const int wid = t >> 6;
  const int wr = wid >> 1, wc = wid & 1;
  const int bid = blockIdx.x;
  const int rb = bid & (FNRB - 1);
  const int s = bid >> 6;
  const int row0 = rb * FBM;
  const int jbase0 = s * FJRANGE;

  bool odd0 = true;
  for (int q = 1; q < 128; q += 2) odd0 = odd0 && (labels[q] == 0);
  const int lstride = odd0 ? 2 : 1;

  int rlab[16];
#pragma unroll
  for (int mi = 0; mi < 4; ++mi)
#pragma unroll
    for (int j = 0; j < 4; ++j)
      rlab[mi * 4 + j] =
          labels[(row0 + wr * 64 + mi * 16 + (l >> 4) * 4 + j) * lstride];

#pragma unroll
  for (int it = 0; it < 8; ++it) {
    int gidx = it * 256 + t;
    int row = gidx >> 4;
    int kg = gidx & 15;
    const float* p = &E[(size_t)(row0 + row) * DIM + kg * 8];
    float4 f0 = *(const float4*)p;
    float4 f1 = *(const float4*)(p + 4);
    u16x8 h, lo;
    cvt8(f0, f1, &h, &lo);
    int off = row * DIM + (kg ^ (row & 7)) * 8;
    *(u16x8*)&Ah[off] = h;
    *(u16x8*)&Al[off] = lo;
  }

  float4 bre[8];
  auto loadB = [&](int jt) {
#pragma unroll
    for (int it = 0; it < 4; ++it) {
      int gidx = it * 256 + t;
      int row = gidx >> 4;
      int kg = gidx & 15;
      const float* p = &E[(size_t)(jbase0 + jt * FBN + row) * DIM + kg * 8];
      bre[2 * it] = *(const float4*)p;
      bre[2 * it + 1] = *(const float4*)(p + 4);
    }
  };
  auto writeB = [&](int buf) {
#pragma unroll
    for (int it = 0; it < 4; ++it) {
      int gidx = it * 256 + t;
      int row = gidx >> 4;
      int kg = gidx & 15;
      u16x8 h, lo;
      cvt8(bre[2 * it], bre[2 * it + 1], &h, &lo);
      int off = row * DIM + (kg ^ (row & 7)) * 8;
      *(u16x8*)&Bhs[buf][off] = h;
      *(u16x8*)&Bls[buf][off] = lo;
    }
  };

  loadB(0);
  writeB(0);
  __syncthreads();

  float minS[16], maxD[16];
#pragma unroll
  for (int i = 0; i < 16; ++i) { minS[i] = 1e30f; maxD[i] = -1e30f; }

  for (int jt = 0; jt < FNT; ++jt) {
    const int buf = jt & 1;
    if (jt + 1 < FNT) loadB(jt + 1);

    f32x4 acc[4][2];
#pragma unroll
    for (int mi = 0; mi < 4; ++mi)
#pragma unroll
      for (int ni = 0; ni < 2; ++ni) acc[mi][ni] = (f32x4){0.f, 0.f, 0.f, 0.f};

#pragma unroll
    for (int ks = 0; ks < 4; ++ks) {
      const int kq = ks * 4 + (l >> 4);
      s16x8 ah[4], al4[4], bh2[2], bl2[2];
#pragma unroll
      for (int mi = 0; mi < 4; ++mi) {
        int row = wr * 64 + mi * 16 + (l & 15);
        int off = row * DIM + (kq ^ (row & 7)) * 8;
        ah[mi] = *(const s16x8*)&Ah[off];
        al4[mi] = *(const s16x8*)&Al[off];
      }
#pragma unroll
      for (int ni = 0; ni < 2; ++ni) {
        int row = wc * 32 + ni * 16 + (l & 15);
        int off = row * DIM + (kq ^ (row & 7)) * 8;
        bh2[ni] = *(const s16x8*)&Bhs[buf][off];
        bl2[ni] = *(const s16x8*)&Bls[buf][off];
      }
#pragma unroll
      for (int mi = 0; mi < 4; ++mi)
#pragma unroll
        for (int ni = 0; ni < 2; ++ni) {
          acc[mi][ni] = __builtin_amdgcn_mfma_f32_16x16x32_bf16(
              ah[mi], bh2[ni], acc[mi][ni], 0, 0, 0);
          acc[mi][ni] = __builtin_amdgcn_mfma_f32_16x16x32_bf16(
              ah[mi], bl2[ni], acc[mi][ni], 0, 0, 0);
          acc[mi][ni] = __builtin_amdgcn_mfma_f32_16x16x32_bf16(
              al4[mi], bh2[ni], acc[mi][ni], 0, 0, 0);
        }
    }

    int clab[2];
#pragma unroll
    for (int ni = 0; ni < 2; ++ni)
      clab[ni] =
          labels[(jbase0 + jt * FBN + wc * 32 + ni * 16 + (l & 15)) * lstride];
#pragma unroll
    for (int mi = 0; mi < 4; ++mi)
#pragma unroll
      for (int j = 0; j < 4; ++j) {
        const int idx = mi * 4 + j;
#pragma unroll
        for (int ni = 0; ni < 2; ++ni) {
          float d = acc[mi][ni][j];
          bool same = (clab[ni] == rlab[idx]);
          minS[idx] = (same && d < minS[idx]) ? d : minS[idx];
          maxD[idx] = (!same && d > maxD[idx]) ? d : maxD[idx];
        }
      }

    if (jt + 1 < FNT) writeB(buf ^ 1);
    __syncthreads();
  }

#pragma unroll
  for (int i = 0; i < 16; ++i) {
    float v0 = minS[i], v1 = maxD[i];
#pragma unroll
    for (int off = 1; off < 16; off <<= 1) {
      v0 = fminf(v0, __shfl_xor(v0, off));
      v1 = fmaxf(v1, __shfl_xor(v1, off));
    }
    minS[i] = v0; maxD[i] = v1;
  }
  if ((l & 15) == 0) {
#pragma unroll
    for (int mi = 0; mi < 4; ++mi)
#pragma unroll
      for (int j = 0; j < 4; ++j) {
        int row = wr * 64 + mi * 16 + (l >> 4) * 4 + j;
        redmin[wc][row] = minS[mi * 4 + j];
        redmax[wc][row] = maxD[mi * 4 + j];
      }
  }
  __syncthreads();
  if (t < FBM) {
    float m = fminf(redmin[0][t], redmin[1][t]);
    float M = fmaxf(redmax[0][t], redmax[1][t]);
    ws[s * NROWS + row0 + t] = m;
    ws[(FJSPLIT + s) * NROWS + row0 + t] = M;
  }
}

__global__ void tl_reduce_fb(const float* __restrict__ ws, float* __restrict__ out) {
  __shared__ float red[256];
  const int t = threadIdx.x;
  float sum = 0.f;
  for (int r = t; r < NROWS; r += 256) {
    float ms = 1e30f, md = -1e30f;
#pragma unroll
    for (int s2 = 0; s2 < FJSPLIT; ++s2) {
      ms = fminf(ms, ws[s2 * NROWS + r]);
      md = fmaxf(md, ws[(FJSPLIT + s2) * NROWS + r]);
    }
    const float hp = fmaxf(1.0f - ms, 0.0f);
    const float hn = 1.0f - md;
    sum += fmaxf(MARGIN_F + hp - hn, 0.0f);
  }
  red[t] = sum;
  __syncthreads();
  for (int off = 128; off > 0; off >>= 1) {
    if (t < off) red[t] += red[t + off];
    __syncthreads();
  }
  if (t == 0) out[0] = red[0] / (float)NROWS;
}

extern "C" void kernel_launch(void* const* d_in, const int* in_sizes, int n_in,
                              void* d_out, int out_size, void* d_ws, size_t ws_size,
                              hipStream_t stream) {
  const float* E = (const float*)d_in[0];
  const int* labels = (const int*)d_in[1];
  float* out = (float*)d_out;

  const size_t HALF = (size_t)NROWS * DIM;  // 1048576 elems
  const size_t partOff = HALF * 4;          // 4MB (Ehi+Elo, 2B each)
  const size_t need = partOff + (size_t)NROWS * 8 * 4 + 4096;

  if (ws_size >= need) {
    unsigned short* Ehi = (unsigned short*)d_ws;
    unsigned short* Elo = Ehi + HALF;
    float* part = (float*)((char*)d_ws + partOff);
    float* partial = part + (size_t)NROWS * 8;
    hipLaunchKernelGGL(tl_split, dim3(512), dim3(256), 0, stream, E, Ehi, Elo);
    hipLaunchKernelGGL(tl_mfma, dim3(NRB2 * JSPLIT2), dim3(512), 0, stream,
                       Ehi, Elo, labels, part);
    hipLaunchKernelGGL(tl_reduce_a, dim3(32), dim3(256), 0, stream, part, partial);
    hipLaunchKernelGGL(tl_reduce_b, dim3(1), dim3(64), 0, stream, partial, out);
  } else {
    float* ws = (float*)d_ws;
    hipLaunchKernelGGL(tl_partial_fb, dim3(FNRB * FJSPLIT), dim3(256), 0, stream,
                       E, labels, ws);
    hipLaunchKernelGGL(tl_reduce_fb, dim3(1), dim3(256), 0, stream, ws, out);
  }
}